// Round 2
// 122.632 us; speedup vs baseline: 1.0394x; 1.0394x over previous
//
#include <hip/hip_runtime.h>
#include <math.h>

#define EPS 1e-7f

constexpr int B = 16, L = 1024, D = 256, P = 20;
constexpr int LD = L * D;     // 262144
constexpr int DD = D * D;     // 65536

typedef __attribute__((ext_vector_type(8))) _Float16 f16x8;
typedef __attribute__((ext_vector_type(4))) float f32x4;

// ---------------------------------------------------------------------------
// 3-kernel pipeline (was 6).  ws layout (float slots):
//   tp  @0        131072   fp32 [32][B][D]   t partials (from k_prep2)
//   CT  @131072   2097152  fp16 [B][D][L]    s2*sqrt(invn2), transposed
//   Gf  @2228224  524288   fp16 [B][D][D]    gram, single pass (no Gp!)
// total 2752512 floats = 11.0 MB.  Eliminated: invU, s1f, Gp, mavh.
// ---------------------------------------------------------------------------

__device__ inline unsigned short f2h(float x) {
    _Float16 h = (_Float16)x;
    union { _Float16 h; unsigned short u; } c; c.h = h; return c.u;
}
__device__ inline float h2f(unsigned short u) {
    union { unsigned short u; _Float16 h; } c; c.u = u; return (float)c.h;
}

// K1: one pass over s2.  Block = 32 full rows (b, m0..m0+31).  Computes
// invn2 locally, emits tp partials and transposed fp16 CT.  Grid 512.
__global__ __launch_bounds__(256) void k_prep2(const float* __restrict__ s2,
                                               float* __restrict__ tp,
                                               unsigned short* __restrict__ CT) {
    __shared__ float tile[32][257];
    __shared__ float wiv[32];   // invn2 = 1/norm
    __shared__ float wsq[32];   // sqrt(invn2)
    int tid = threadIdx.x;
    int b   = blockIdx.x >> 5, mt = blockIdx.x & 31;
    int m0  = mt * 32;
    {
        int r = tid >> 3, c0 = (tid & 7) * 32;
        const float* gp = s2 + (size_t)b * LD + (size_t)(m0 + r) * D + c0;
        float4 v[8];
#pragma unroll
        for (int q = 0; q < 8; ++q) v[q] = ((const float4*)gp)[q];
#pragma unroll
        for (int q = 0; q < 8; ++q) *(float4*)&tile[r][c0 + q * 4] = v[q];
    }
    __syncthreads();
    {
        int r = tid >> 3, seg = tid & 7;
        float s = 0.f;
#pragma unroll
        for (int k = 0; k < 32; ++k) { float v = tile[r][seg * 32 + k]; s += v * v; }
#pragma unroll
        for (int o = 4; o; o >>= 1) s += __shfl_down(s, o, 8);
        if (seg == 0) {
            float iv = 1.0f / sqrtf(fmaxf(s, EPS));
            wiv[r] = iv;
            wsq[r] = sqrtf(iv);
        }
    }
    __syncthreads();
    {
        int dc = tid;                          // d-column 0..255
        float tpart = 0.f;
        union { unsigned short us[32]; uint4 q[4]; } ph;
#pragma unroll
        for (int m = 0; m < 32; ++m) {
            float v = tile[m][dc];
            tpart += v * wiv[m];
            ph.us[m] = f2h(v * wsq[m]);
        }
        tp[(size_t)(mt * B + b) * D + dc] = tpart;
        size_t o = (size_t)b * LD + (size_t)dc * L + m0;
        *(uint4*)(CT + o)      = ph.q[0]; *(uint4*)(CT + o + 8)  = ph.q[1];
        *(uint4*)(CT + o + 16) = ph.q[2]; *(uint4*)(CT + o + 24) = ph.q[3];
    }
}

// K2: SINGLE-PASS gram  G = C C^T  (fp16 MFMA, fp32 accum), no global
// partials.  32x32 output tile; the 4 waves split K (each wave owns two
// 32-wide K slices of each staged 256-K chunk), LDS-reduce at the end.
// Grid = 16 b x 8 ti x 8 tj = 1024 blocks (≈4 blocks/CU).  LDS 33.8 KB.
__global__ __launch_bounds__(256) void k_gram32(const unsigned short* __restrict__ CT,
                                                unsigned short* __restrict__ Gf) {
    __shared__ short smem[2 * 32 * 264];   // As @0, Bs @32*264; red overlays after
    short* As = smem;
    short* Bs = smem + 32 * 264;
    int tid  = threadIdx.x;
    int b    = blockIdx.x >> 6;
    int ti   = (blockIdx.x >> 3) & 7;
    int tj   = blockIdx.x & 7;
    int wave = tid >> 6, lane = tid & 63;
    int lr   = lane & 15, lq = lane >> 4;
    int srow = tid >> 3, sseg = (tid & 7) * 32;

    f32x4 acc[2][2];
#pragma unroll
    for (int i = 0; i < 2; ++i)
#pragma unroll
        for (int j = 0; j < 2; ++j) acc[i][j] = (f32x4){0.f, 0.f, 0.f, 0.f};

#pragma unroll 1
    for (int kb = 0; kb < 4; ++kb) {
        int koff = kb * 256;
        __syncthreads();
        {
            // stage 32 shorts (4 x uint4) per thread per buffer
            const unsigned short* ga = CT + (size_t)b * LD + (size_t)(ti * 32 + srow) * L + koff + sseg;
            uint4 a0 = ((const uint4*)ga)[0], a1 = ((const uint4*)ga)[1];
            uint4 a2 = ((const uint4*)ga)[2], a3 = ((const uint4*)ga)[3];
            const unsigned short* gb = CT + (size_t)b * LD + (size_t)(tj * 32 + srow) * L + koff + sseg;
            uint4 b0 = ((const uint4*)gb)[0], b1 = ((const uint4*)gb)[1];
            uint4 b2 = ((const uint4*)gb)[2], b3 = ((const uint4*)gb)[3];
            short* la = &As[srow * 264 + sseg];
            ((uint4*)la)[0] = a0; ((uint4*)la)[1] = a1;
            ((uint4*)la)[2] = a2; ((uint4*)la)[3] = a3;
            short* lb = &Bs[srow * 264 + sseg];
            ((uint4*)lb)[0] = b0; ((uint4*)lb)[1] = b1;
            ((uint4*)lb)[2] = b2; ((uint4*)lb)[3] = b3;
        }
        __syncthreads();
#pragma unroll
        for (int kk = 0; kk < 2; ++kk) {
            int ks = wave * 2 + kk;            // this wave's K slice
            f16x8 af[2], bf[2];
#pragma unroll
            for (int i = 0; i < 2; ++i)
                af[i] = *(const f16x8*)&As[(i * 16 + lr) * 264 + ks * 32 + lq * 8];
#pragma unroll
            for (int j = 0; j < 2; ++j)
                bf[j] = *(const f16x8*)&Bs[(j * 16 + lr) * 264 + ks * 32 + lq * 8];
#pragma unroll
            for (int i = 0; i < 2; ++i)
#pragma unroll
                for (int j = 0; j < 2; ++j)
                    acc[i][j] = __builtin_amdgcn_mfma_f32_16x16x32_f16(af[i], bf[j], acc[i][j], 0, 0, 0);
        }
    }
    __syncthreads();                           // all MFMA reads done -> reuse smem
    float* red = (float*)smem;                 // [4][32][33] fp32 = 16.9 KB
#pragma unroll
    for (int i = 0; i < 2; ++i)
#pragma unroll
        for (int j = 0; j < 2; ++j)
#pragma unroll
            for (int r = 0; r < 4; ++r) {
                int row = i * 16 + lq * 4 + r, col = j * 16 + lr;
                red[wave * 1056 + row * 33 + col] = acc[i][j][r];
            }
    __syncthreads();
#pragma unroll
    for (int k = 0; k < 4; ++k) {
        int e = tid + k * 256;
        int row = e >> 5, col = e & 31;
        float s = red[row * 33 + col] + red[1056 + row * 33 + col] +
                  red[2112 + row * 33 + col] + red[3168 + row * 33 + col];
        Gf[(size_t)b * DD + (size_t)(ti * 32 + row) * D + tj * 32 + col] = f2h(s);
    }
}

// K3: FUSED  mav = s1 @ G  +  perspective-cosine output.
// Block = 64 l rows (full D), 512 threads (8 waves, 2 waves/SIMD).
//   a) reduce tp -> t (per block, L2-resident, cheap)
//   b) stage s1 fp32 -> fp16 As, inline up = s1·t and sq = |s1|^2 -> sign
//   c) GEMM over 4 n-quarters of G (64 n each); mav rows -> Ms (fp16 LDS)
//   d) k2s overlay on Bs; per-row epilogue identical to old k_out
// Grid = 16 b x 16 lt = 256.  LDS ≈ 100 KB -> 1 block/CU.
__global__ __launch_bounds__(512) void k_mav_out(const float* __restrict__ s1,
                                                 const float* __restrict__ tp,
                                                 const unsigned short* __restrict__ Gf,
                                                 const float* __restrict__ kern,
                                                 float* __restrict__ out) {
    __shared__ short As[64 * 264];   // s1 fp16, resident through epilogue
    __shared__ short Bs[64 * 264];   // G quarter (GEMM) / k2s overlay (epilogue)
    __shared__ short Ms[64 * 264];   // mav fp16
    __shared__ float ts[D];
    __shared__ float sgnS[64];
    int tid  = threadIdx.x;
    int b    = blockIdx.x >> 4, lt = blockIdx.x & 15;
    int l0   = lt * 64;
    int wave = tid >> 6, lane = tid & 63;
    int lr   = lane & 15, lq = lane >> 4;

    // (a) t[d] = sum_mc tp[mc][b][d]
    if (tid < 256) {
        float a = 0.f;
#pragma unroll
        for (int mc = 0; mc < 32; ++mc) a += tp[(size_t)(mc * B + b) * D + tid];
        ts[tid] = a;
    }
    __syncthreads();

    // (b) stage s1 -> As fp16; per-row up/sq -> sign of (up + EPS*n1)
    {
        int r = tid >> 3, seg = tid & 7;       // 64 rows x 8 threads x 32 floats
        const float* gp = s1 + (size_t)(b * L + l0 + r) * D + seg * 32;
        float up = 0.f, sq = 0.f;
        union { unsigned short us[32]; uint4 q[4]; } hb;
#pragma unroll
        for (int q8 = 0; q8 < 8; ++q8) {
            float4 v = ((const float4*)gp)[q8];
            int td = seg * 32 + q8 * 4;
            up += v.x * ts[td] + v.y * ts[td + 1] + v.z * ts[td + 2] + v.w * ts[td + 3];
            sq += v.x * v.x + v.y * v.y + v.z * v.z + v.w * v.w;
            hb.us[q8 * 4 + 0] = f2h(v.x); hb.us[q8 * 4 + 1] = f2h(v.y);
            hb.us[q8 * 4 + 2] = f2h(v.z); hb.us[q8 * 4 + 3] = f2h(v.w);
        }
        short* la = &As[r * 264 + seg * 32];
        ((uint4*)la)[0] = hb.q[0]; ((uint4*)la)[1] = hb.q[1];
        ((uint4*)la)[2] = hb.q[2]; ((uint4*)la)[3] = hb.q[3];
#pragma unroll
        for (int o = 4; o; o >>= 1) { up += __shfl_down(up, o, 8); sq += __shfl_down(sq, o, 8); }
        if (seg == 0) {
            float n1v = sqrtf(fmaxf(sq, EPS));
            sgnS[r] = up + EPS * n1v;          // only the sign is ever used
        }
    }

    // (c) mav rows: 8 waves as 2(l-groups of 32) x 4(n-groups of 16)
    int wlr = (wave >> 2) * 32;
    int wnc = (wave & 3) * 16;
#pragma unroll 1
    for (int nh = 0; nh < 4; ++nh) {
        __syncthreads();                        // prior Bs reads done / As visible
        {
            // stage 32 shorts (4 x uint4) per thread: 64 rows x 256 shorts
            int r = tid >> 3, seg = (tid & 7) * 32;
            const unsigned short* gb = Gf + (size_t)b * DD + (size_t)(nh * 64 + r) * D + seg;
            uint4 b0 = ((const uint4*)gb)[0], b1 = ((const uint4*)gb)[1];
            uint4 b2 = ((const uint4*)gb)[2], b3 = ((const uint4*)gb)[3];
            short* lb = &Bs[r * 264 + seg];
            ((uint4*)lb)[0] = b0; ((uint4*)lb)[1] = b1;
            ((uint4*)lb)[2] = b2; ((uint4*)lb)[3] = b3;
        }
        __syncthreads();
        f32x4 acc[2];
        acc[0] = (f32x4){0.f, 0.f, 0.f, 0.f};
        acc[1] = (f32x4){0.f, 0.f, 0.f, 0.f};
#pragma unroll
        for (int ks = 0; ks < 8; ++ks) {
            f16x8 af0 = *(const f16x8*)&As[(wlr + lr) * 264 + ks * 32 + lq * 8];
            f16x8 af1 = *(const f16x8*)&As[(wlr + 16 + lr) * 264 + ks * 32 + lq * 8];
            f16x8 bf  = *(const f16x8*)&Bs[(wnc + lr) * 264 + ks * 32 + lq * 8];
            acc[0] = __builtin_amdgcn_mfma_f32_16x16x32_f16(af0, bf, acc[0], 0, 0, 0);
            acc[1] = __builtin_amdgcn_mfma_f32_16x16x32_f16(af1, bf, acc[1], 0, 0, 0);
        }
#pragma unroll
        for (int i = 0; i < 2; ++i)
#pragma unroll
            for (int r4 = 0; r4 < 4; ++r4)
                Ms[(wlr + i * 16 + lq * 4 + r4) * 264 + nh * 64 + wnc + lr] = f2h(acc[i][r4]);
    }
    __syncthreads();                            // Bs free, Ms complete

    // (d) k2s overlay (padded stride 264 to dodge 4-way bank conflict)
    float* k2s = (float*)Bs;
    {
        int d = tid & 255, ph = tid >> 8;
#pragma unroll
        for (int i = 0; i < 10; ++i) {
            int p = i * 2 + ph;
            float v = kern[p * D + d];
            k2s[p * 264 + d] = v * v;
        }
    }
    __syncthreads();

    int dg = lane & 15, ps = lane >> 4;
#pragma unroll 1
    for (int rl = 0; rl < 8; ++rl) {
        int l = wave * 8 + rl;
        float4 sm[4], ss[4], mm[4];
#pragma unroll
        for (int j = 0; j < 4; ++j) {
            ushort4 h4 = *(const ushort4*)&As[l * 264 + dg * 4 + j * 64];
            ushort4 m4 = *(const ushort4*)&Ms[l * 264 + dg * 4 + j * 64];
            float4 sv, mv;
            sv.x = h2f(h4.x); sv.y = h2f(h4.y); sv.z = h2f(h4.z); sv.w = h2f(h4.w);
            mv.x = h2f(m4.x); mv.y = h2f(m4.y); mv.z = h2f(m4.z); mv.w = h2f(m4.w);
            sm[j].x = sv.x * mv.x; sm[j].y = sv.y * mv.y; sm[j].z = sv.z * mv.z; sm[j].w = sv.w * mv.w;
            ss[j].x = sv.x * sv.x; ss[j].y = sv.y * sv.y; ss[j].z = sv.z * sv.z; ss[j].w = sv.w * sv.w;
            mm[j].x = mv.x * mv.x; mm[j].y = mv.y * mv.y; mm[j].z = mv.z * mv.z; mm[j].w = mv.w * mv.w;
        }
        float sgn = (sgnS[l] < 0.f) ? -1.f : 1.f;
#pragma unroll
        for (int tI = 0; tI < 5; ++tI) {
            int p = ps + tI * 4;
            float na = 0.f, nb = 0.f, nc = 0.f;
#pragma unroll
            for (int j = 0; j < 4; ++j) {
                float4 kv = *(const float4*)&k2s[p * 264 + j * 64 + dg * 4];
                na += sm[j].x * kv.x + sm[j].y * kv.y + sm[j].z * kv.z + sm[j].w * kv.w;
                nb += ss[j].x * kv.x + ss[j].y * kv.y + ss[j].z * kv.z + ss[j].w * kv.w;
                nc += mm[j].x * kv.x + mm[j].y * kv.y + mm[j].z * kv.z + mm[j].w * kv.w;
            }
#pragma unroll
            for (int o = 8; o; o >>= 1) {
                na += __shfl_down(na, o, 16);
                nb += __shfl_down(nb, o, 16);
                nc += __shfl_down(nc, o, 16);
            }
            if (dg == 0) {
                out[(size_t)(b * L + l0 + l) * P + p] =
                    sgn * na * rsqrtf(fmaxf(nb, EPS)) * rsqrtf(fmaxf(nc, EPS));
            }
        }
    }
}

extern "C" void kernel_launch(void* const* d_in, const int* in_sizes, int n_in,
                              void* d_out, int out_size, void* d_ws, size_t ws_size,
                              hipStream_t stream) {
    const float* s1   = (const float*)d_in[0];
    const float* s2   = (const float*)d_in[1];
    const float* kern = (const float*)d_in[2];
    float* out = (float*)d_out;
    float* ws  = (float*)d_ws;

    float* tp = ws;                                            // 131072 f
    unsigned short* CT = (unsigned short*)(ws + 131072);       // 4194304 h
    unsigned short* Gf = (unsigned short*)(ws + 2228224);      // 1048576 h

    k_prep2<<<512, 256, 0, stream>>>(s2, tp, CT);
    k_gram32<<<1024, 256, 0, stream>>>(CT, Gf);
    k_mav_out<<<256, 512, 0, stream>>>(s1, tp, Gf, kern, out);
}